// Round 5
// baseline (153.483 us; speedup 1.0000x reference)
//
#include <hip/hip_runtime.h>

#define B_ 8
#define CIN_ 256
#define COUT_ 256

typedef short short8_t __attribute__((ext_vector_type(8)));
typedef float float16_t __attribute__((ext_vector_type(16)));

// ws layout (shorts): dwA [0, DWA_SHORTS) ; xpre [DWA_SHORTS, +XPRE_SHORTS)
#define DWA_SHORTS   (B_ * 9 * 32 * COUT_ * 8)      // 4,718,592
#define XPRE_SHORTS  (B_ * 8 * 66 * 66 * 32)        // 8,921,088

__device__ __forceinline__ unsigned short f2bf(float f) {
    union { float f; unsigned u; } v; v.f = f;
    unsigned u = v.u;
    unsigned r = (u + 0x7fffu + ((u >> 16) & 1u)) >> 16;  // RNE
    return (unsigned short)r;
}

// Fused prep: blocks [0,4224) pack x -> xpre bf16 [b][cb8][h66][w66][ci32]
// (halo zeros written); blocks [4224,4288) do modulate+demodulate -> dwA
// bf16 [b][tap9][oct32][co256][ci8].
__global__ __launch_bounds__(256) void k_prep(const float* __restrict__ x,
                                              const float* __restrict__ style,
                                              const float* __restrict__ weight,
                                              unsigned short* __restrict__ xpre,
                                              unsigned short* __restrict__ dwA) {
    __shared__ float wlds[4 * 2304];  // used by modulate blocks only
    const int bid = blockIdx.x;
    const int t = threadIdx.x;

    if (bid < 4224) {  // ---- xpre part ----
        const int h_out = bid % 66;
        const int t2 = bid / 66;
        const int cb = t2 & 7, b = t2 >> 3;
        const int h_in = h_out - 1;
        unsigned short* dst_row = xpre + ((size_t)(b * 8 + cb) * 66 + h_out) * 66 * 32;
#pragma unroll
        for (int pass = 0; pass < 2; ++pass) {
            int p = t + pass * 256;
            if (p >= 264) break;
            int w_out = p >> 2, g = p & 3;
            int w_in = w_out - 1;
            short8_t v = (short8_t){0, 0, 0, 0, 0, 0, 0, 0};
            if ((unsigned)h_in < 64u && (unsigned)w_in < 64u) {
                const float* xp =
                    x + (((size_t)(b * CIN_ + cb * 32 + g * 8)) * 64 + h_in) * 64 + w_in;
#pragma unroll
                for (int j = 0; j < 8; ++j) v[j] = (short)f2bf(xp[(size_t)j * 4096]);
            }
            *(short8_t*)(dst_row + (size_t)w_out * 32 + g * 8) = v;
        }
    } else {  // ---- modulate part ----
        const int co0 = (bid - 4224) * 4;
        const int co_l = t >> 6;
        const int lane = t & 63;
        const int co = co0 + co_l;

        const float* wp = weight + (size_t)co0 * 2304;
#pragma unroll
        for (int k = 0; k < 36; ++k) wlds[t + 256 * k] = wp[t + 256 * k];
        __syncthreads();

        float wv[4][9];
        float ss[4];
#pragma unroll
        for (int k = 0; k < 4; ++k) {
            float a = 0.f;
#pragma unroll
            for (int tap = 0; tap < 9; ++tap) {
                float w = wlds[co_l * 2304 + (lane + 64 * k) * 9 + tap];
                wv[k][tap] = w;
                a += w * w;
            }
            ss[k] = a;
        }
        float sv[8][4];
#pragma unroll
        for (int b = 0; b < 8; ++b)
#pragma unroll
            for (int k = 0; k < 4; ++k) sv[b][k] = style[b * CIN_ + lane + 64 * k];

        float inv[8];
#pragma unroll
        for (int b = 0; b < 8; ++b) {
            float part = 0.f;
#pragma unroll
            for (int k = 0; k < 4; ++k) part += sv[b][k] * sv[b][k] * ss[k];
#pragma unroll
            for (int off = 32; off > 0; off >>= 1) part += __shfl_xor(part, off, 64);
            inv[b] = 1.0f / sqrtf(part + 1e-8f);
        }

        const size_t base = (size_t)co * 8 + (lane & 7) + (size_t)(lane >> 3) * 2048;
#pragma unroll
        for (int b = 0; b < 8; ++b)
#pragma unroll
            for (int tap = 0; tap < 9; ++tap)
#pragma unroll
                for (int k = 0; k < 4; ++k) {
                    size_t addr = ((size_t)(b * 9 + tap) * 32 + k * 8) * 2048 + base;
                    dwA[addr] = f2bf(wv[k][tap] * sv[b][k] * inv[b]);
                }
    }
}

// Conv: 1024 blocks (row64, co_tile2, b8), 4 waves = 2(co64) x 2(col32).
// mfma_f32_32x32x16_bf16, K-slabs of 16; LDS x-tile chunk-linear
// [row3][g4][col66][8] -> every b128 access is lane-contiguous (0 conflicts).
__global__ __launch_bounds__(256, 4) void k_conv(const unsigned short* __restrict__ xpre,
                                                 const unsigned short* __restrict__ dwA,
                                                 float* __restrict__ out) {
    __shared__ __align__(16) unsigned short xs[2][12 * 66 * 8];  // 2 x 12.4 KB

    const int row = blockIdx.x;      // output row 0..63
    const int co_tile = blockIdx.y;  // 0..1
    const int b = blockIdx.z;        // 0..7
    const int tid = threadIdx.x;
    const int lane = tid & 63, wid = tid >> 6;
    const int wave_m = wid >> 1, wave_n = wid & 1;
    const int l32 = lane & 31, kh = lane >> 5;
    const int co_base = co_tile * 128 + wave_m * 64;

    float16_t acc[2];
#pragma unroll
    for (int mi = 0; mi < 2; ++mi)
#pragma unroll
        for (int r = 0; r < 16; ++r) acc[mi][r] = 0.f;

    // staging: 792 16B chunks (3 rows x 4 g x 66 cols), chunk-linear in LDS
    short8_t st[4];
    auto load_regs = [&](int cb) {
        const unsigned short* s = xpre + (((size_t)(b * 8 + cb) * 66 + row)) * (66 * 32);
#pragma unroll
        for (int it = 0; it < 3; ++it) {
            int c = tid + it * 256;
            int rowg = c / 66;
            int col = c - rowg * 66;
            st[it] = *(const short8_t*)(s + (size_t)((rowg >> 2) * 2112 + col * 32 + (rowg & 3) * 8));
        }
        if (tid < 24) {
            int c = tid + 768;
            int rowg = c / 66;
            int col = c - rowg * 66;
            st[3] = *(const short8_t*)(s + (size_t)((rowg >> 2) * 2112 + col * 32 + (rowg & 3) * 8));
        }
    };
    auto store_lds = [&](int buf) {
        unsigned short* d = xs[buf];
#pragma unroll
        for (int it = 0; it < 3; ++it)
            *(short8_t*)(d + (size_t)(tid + it * 256) * 8) = st[it];
        if (tid < 24) *(short8_t*)(d + (size_t)(tid + 768) * 8) = st[3];
    };

    // A frags: rotation indexed by GLOBAL step parity (cb*9+tap ≡ cb+tap mod 2).
    // (9 is odd — indexing by tap&1 alone desyncs at each cb boundary.)
    short8_t abuf[2][4];
    auto loadA = [&](short8_t* dst, int acb, int atap) {
        const unsigned short* base = dwA + ((size_t)(b * 9 + atap) * 32 + acb * 4 + kh) * 2048;
#pragma unroll
        for (int mi = 0; mi < 2; ++mi)
#pragma unroll
            for (int ks = 0; ks < 2; ++ks)
                dst[mi * 2 + ks] =
                    *(const short8_t*)(base + (size_t)ks * 4096 + (co_base + mi * 32 + l32) * 8);
    };

    load_regs(0);
    loadA(abuf[0], 0, 0);  // step L=0 -> abuf[0]

    for (int cb = 0; cb < 8; ++cb) {
        store_lds(cb & 1);
        __syncthreads();
        if (cb < 7) load_regs(cb + 1);

        const unsigned short* xb = xs[cb & 1];
#pragma unroll
        for (int tap = 0; tap < 9; ++tap) {
            const int par = (cb + tap) & 1;  // global-step parity
            // prefetch next step's A (linearized across cb boundary)
            const int nl = tap + 1;
            const int acb = cb + nl / 9, atap = nl % 9;
            if (acb < 8) loadA(abuf[par ^ 1], acb, atap);

            const int dh = tap / 3, dwc = tap - dh * 3;
            const int col = wave_n * 32 + l32 + dwc;
            short8_t bf[2];
#pragma unroll
            for (int ks = 0; ks < 2; ++ks) {
                int g = ks * 2 + kh;
                bf[ks] = *(const short8_t*)(xb + (size_t)((dh * 4 + g) * 66 + col) * 8);
            }
            const short8_t* ac = abuf[par];
#pragma unroll
            for (int ks = 0; ks < 2; ++ks)
#pragma unroll
                for (int mi = 0; mi < 2; ++mi)
                    acc[mi] = __builtin_amdgcn_mfma_f32_32x32x16_bf16(ac[mi * 2 + ks], bf[ks],
                                                                      acc[mi], 0, 0, 0);
        }
    }

    // epilogue: 32x32 C/D: col = lane&31, co_off = (r&3) + 8*(r>>2) + 4*kh
    const int colb = wave_n * 32 + l32;
#pragma unroll
    for (int mi = 0; mi < 2; ++mi)
#pragma unroll
        for (int r = 0; r < 16; ++r) {
            int co = co_base + mi * 32 + (r & 3) + 8 * (r >> 2) + 4 * kh;
            out[(((size_t)b * COUT_ + co) * 64 + row) * 64 + colb] = acc[mi][r];
        }
}

extern "C" void kernel_launch(void* const* d_in, const int* in_sizes, int n_in,
                              void* d_out, int out_size, void* d_ws, size_t ws_size,
                              hipStream_t stream) {
    const float* x = (const float*)d_in[0];
    const float* style = (const float*)d_in[1];
    const float* weight = (const float*)d_in[2];
    float* out = (float*)d_out;

    unsigned short* dwA = (unsigned short*)d_ws;
    unsigned short* xpre = dwA + DWA_SHORTS;

    k_prep<<<dim3(4288), 256, 0, stream>>>(x, style, weight, xpre, dwA);
    k_conv<<<dim3(64, 2, B_), 256, 0, stream>>>(xpre, dwA, out);
}

// Round 6
// 152.813 us; speedup vs baseline: 1.0044x; 1.0044x over previous
//
#include <hip/hip_runtime.h>

#define B_ 8
#define CIN_ 256
#define COUT_ 256

typedef short short8_t __attribute__((ext_vector_type(8)));
typedef float float16_t __attribute__((ext_vector_type(16)));

// ws layout (shorts): dwA [0, DWA) ; xpre [DWA, DWA+XPRE) ; inv fp32 after.
#define DWA_SHORTS   (B_ * 2 * 8 * 9 * 4 * 128 * 8)   // 4,718,592
#define XPRE_SHORTS  (B_ * 8 * 66 * 4 * 66 * 8)       // 8,921,088

__device__ __forceinline__ unsigned short f2bf(float f) {
    union { float f; unsigned u; } v; v.f = f;
    unsigned u = v.u;
    unsigned r = (u + 0x7fffu + ((u >> 16) & 1u)) >> 16;  // RNE
    return (unsigned short)r;
}

// K1 fused: blocks [0,4224): pack x -> xpre bf16 [b][cb8][h66][g4][w66][ci8]
// (halos written as zeros; lane = w so every read/write is coalesced).
// blocks [4224,4240): inv[b][co] = 1/sqrt(sum_ci s^2 * sum_tap w^2 + 1e-8).
__global__ __launch_bounds__(256) void k_prep(const float* __restrict__ x,
                                              const float* __restrict__ style,
                                              const float* __restrict__ weight,
                                              unsigned short* __restrict__ xpre,
                                              float* __restrict__ invp) {
    const int bid = blockIdx.x;
    const int t = threadIdx.x;

    if (bid < 4224) {  // ---- xpre pack ----
        const int h_out = bid % 66;
        const int t2 = bid / 66;
        const int cb = t2 & 7, b = t2 >> 3;
        const int h_in = h_out - 1;
        const int g = t >> 6, lane = t & 63;
        unsigned short* dst =
            xpre + (((size_t)(b * 8 + cb) * 66 + h_out) * 4 + g) * (66 * 8);
#pragma unroll
        for (int pass = 0; pass < 2; ++pass) {
            int w_out = pass * 64 + lane;
            if (pass == 1 && lane >= 2) break;
            int w_in = w_out - 1;
            short8_t v = (short8_t){0, 0, 0, 0, 0, 0, 0, 0};
            if ((unsigned)h_in < 64u && (unsigned)w_in < 64u) {
                const float* xp =
                    x + (((size_t)(b * CIN_ + cb * 32 + g * 8)) * 64 + h_in) * 64 + w_in;
#pragma unroll
                for (int j = 0; j < 8; ++j) v[j] = (short)f2bf(xp[(size_t)j * 4096]);
            }
            *(short8_t*)(dst + (size_t)w_out * 8) = v;
        }
    } else {  // ---- inv ----
        const int co = (bid - 4224) * 16 + (t >> 4);
        const int sl = t & 15;
        float part[8];
#pragma unroll
        for (int b = 0; b < 8; ++b) part[b] = 0.f;
        const float* wr = weight + (size_t)co * 2304 + sl * 16 * 9;
#pragma unroll 4
        for (int k = 0; k < 16; ++k) {
            int ci = sl * 16 + k;
            float a = 0.f;
#pragma unroll
            for (int tp = 0; tp < 9; ++tp) { float w = wr[k * 9 + tp]; a += w * w; }
#pragma unroll
            for (int b = 0; b < 8; ++b) {
                float s = style[b * CIN_ + ci];
                part[b] += s * s * a;
            }
        }
#pragma unroll
        for (int b = 0; b < 8; ++b) {
            float p = part[b];
            p += __shfl_xor(p, 1, 64);
            p += __shfl_xor(p, 2, 64);
            p += __shfl_xor(p, 4, 64);
            p += __shfl_xor(p, 8, 64);
            if (sl == 0) invp[b * COUT_ + co] = 1.0f / sqrtf(p + 1e-8f);
        }
    }
}

// K2: modulated weights -> dwA bf16 [b][co_blk2][cb8][tap9][g4][co128][ci8].
// Writes: thread-linear over the 36864-short slab -> 16B/lane coalesced.
__global__ __launch_bounds__(256) void k_wpack(const float* __restrict__ weight,
                                               const float* __restrict__ style,
                                               const float* __restrict__ invp,
                                               unsigned short* __restrict__ dwA) {
    const int co_blk = blockIdx.x, cb = blockIdx.y, b = blockIdx.z;
    const int t = threadIdx.x;
    unsigned short* slab = dwA + (((size_t)(b * 2 + co_blk) * 8 + cb) * 9) * 4096;
    const int co = co_blk * 128 + (t & 127);
    const float iv = invp[b * COUT_ + co];
    const float* wco = weight + (size_t)co * 2304;
#pragma unroll
    for (int i = 0; i < 18; ++i) {
        int o8 = t + i * 256;           // [tap][g][co128] octet index
        int g = (o8 >> 7) & 3;
        int tap = o8 >> 9;
        int ci0 = cb * 32 + g * 8;
        short8_t v;
#pragma unroll
        for (int k = 0; k < 8; ++k)
            v[k] = (short)f2bf(wco[(ci0 + k) * 9 + tap] * style[b * CIN_ + ci0 + k] * iv);
        *(short8_t*)(slab + (size_t)o8 * 8) = v;
    }
}

// K3: conv as 9 shifted GEMMs. Block = 128 co x 2 rows; 4 waves = 2(co64) x
// 2(row); wave = M64 x N64 via mi2 x nj2 of mfma_f32_32x32x16_bf16.
// B from LDS (uniform banks), A from global with depth-3/distance-2 prefetch.
__global__ __launch_bounds__(256, 2) void k_conv(const unsigned short* __restrict__ xpre,
                                                 const unsigned short* __restrict__ dwA,
                                                 float* __restrict__ out) {
    __shared__ __align__(16) unsigned short xs[2][4 * 4 * 66 * 8];  // 2 x 16.9 KB

    const int rowgrp = blockIdx.x;   // 0..31
    const int co_blk = blockIdx.y;   // 0..1
    const int b = blockIdx.z;        // 0..7
    const int tid = threadIdx.x;
    const int lane = tid & 63, wid = tid >> 6;
    const int wave_m = wid & 1;      // co64 half
    const int wave_r = wid >> 1;     // output row within rowgrp
    const int l32 = lane & 31, kh = lane >> 5;
    const int r0 = rowgrp * 2;

    float16_t acc[2][2];
#pragma unroll
    for (int mi = 0; mi < 2; ++mi)
#pragma unroll
        for (int nj = 0; nj < 2; ++nj)
#pragma unroll
            for (int r = 0; r < 16; ++r) acc[mi][nj][r] = 0.f;

    // staging: per cb the xpre slice (4 h-rows) is one contiguous 8448-short slab
    short8_t st[5];
    auto load_regs = [&](int cb) {
        const unsigned short* s =
            xpre + ((size_t)(b * 8 + cb) * 66 + r0) * (4 * 66 * 8);
#pragma unroll
        for (int it = 0; it < 4; ++it)
            st[it] = *(const short8_t*)(s + (size_t)(tid + it * 256) * 8);
        if (tid < 32) st[4] = *(const short8_t*)(s + (size_t)(tid + 1024) * 8);
    };
    auto store_lds = [&](int buf) {
        unsigned short* d = xs[buf];
#pragma unroll
        for (int it = 0; it < 4; ++it)
            *(short8_t*)(d + (size_t)(tid + it * 256) * 8) = st[it];
        if (tid < 32) *(short8_t*)(d + (size_t)(tid + 1024) * 8) = st[4];
    };

    // A frags: abuf[depth3][ks*2+mi]; A[m=lane&31][k=kh*8+j], ci-oct g = ks*2+kh
    short8_t abuf[3][4];
    auto loadA = [&](short8_t* dst, int acb, int atap) {
        const unsigned short* Ab =
            dwA + ((((size_t)(b * 2 + co_blk) * 8 + acb) * 9 + atap)) * 4096;
        const int co_off = wave_m * 64 + l32;
#pragma unroll
        for (int ks = 0; ks < 2; ++ks)
#pragma unroll
            for (int mi = 0; mi < 2; ++mi)
                dst[ks * 2 + mi] = *(const short8_t*)(
                    Ab + (size_t)((ks * 2 + kh) * 128 + co_off + mi * 32) * 8);
    };

    load_regs(0);
    loadA(abuf[0], 0, 0);
    loadA(abuf[1], 0, 1);

    for (int cb = 0; cb < 8; ++cb) {
        store_lds(cb & 1);
        __syncthreads();
        if (cb < 7) load_regs(cb + 1);

        const unsigned short* xb = xs[cb & 1];
#pragma unroll
        for (int tap = 0; tap < 9; ++tap) {
            // distance-2 prefetch; tap%3 rotation is cb-consistent (9%3==0)
            const int nl = tap + 2;
            const int acb = cb + nl / 9, atap = nl % 9;
            if (acb < 8) loadA(abuf[(tap + 2) % 3], acb, atap);

            const int dh = tap / 3, dwc = tap - dh * 3;
            // B[k][n]: n=l32 (col), k=kh*8+j; g = ks*2+kh; row = wave_r+dh
            const unsigned short* bb =
                xb + (size_t)(((wave_r + dh) * 4 + kh) * 66 + l32 + dwc) * 8;
            short8_t bf[2][2];
#pragma unroll
            for (int ks = 0; ks < 2; ++ks)
#pragma unroll
                for (int nj = 0; nj < 2; ++nj)
                    bf[ks][nj] = *(const short8_t*)(bb + (size_t)(ks * 2 * 66 + nj * 32) * 8);

            const short8_t* ac = abuf[tap % 3];
#pragma unroll
            for (int ks = 0; ks < 2; ++ks)
#pragma unroll
                for (int mi = 0; mi < 2; ++mi)
#pragma unroll
                    for (int nj = 0; nj < 2; ++nj)
                        acc[mi][nj] = __builtin_amdgcn_mfma_f32_32x32x16_bf16(
                            ac[ks * 2 + mi], bf[ks][nj], acc[mi][nj], 0, 0, 0);
        }
    }

    // epilogue: 32x32 C/D: col = lane&31, co_off = (r&3) + 8*(r>>2) + 4*kh
    const int orow = r0 + wave_r;
#pragma unroll
    for (int mi = 0; mi < 2; ++mi)
#pragma unroll
        for (int nj = 0; nj < 2; ++nj)
#pragma unroll
            for (int r = 0; r < 16; ++r) {
                int co = co_blk * 128 + wave_m * 64 + mi * 32 + (r & 3) + 8 * (r >> 2) + 4 * kh;
                int c = nj * 32 + l32;
                out[(((size_t)b * COUT_ + co) * 64 + orow) * 64 + c] = acc[mi][nj][r];
            }
}

extern "C" void kernel_launch(void* const* d_in, const int* in_sizes, int n_in,
                              void* d_out, int out_size, void* d_ws, size_t ws_size,
                              hipStream_t stream) {
    const float* x = (const float*)d_in[0];
    const float* style = (const float*)d_in[1];
    const float* weight = (const float*)d_in[2];
    float* out = (float*)d_out;

    unsigned short* dwA = (unsigned short*)d_ws;
    unsigned short* xpre = dwA + DWA_SHORTS;
    float* invp = (float*)(xpre + XPRE_SHORTS);

    k_prep<<<dim3(4240), 256, 0, stream>>>(x, style, weight, xpre, invp);
    k_wpack<<<dim3(2, 8, B_), 256, 0, stream>>>(weight, style, invp, dwA);
    k_conv<<<dim3(32, 2, B_), 256, 0, stream>>>(xpre, dwA, out);
}